// Round 22
// baseline (193.409 us; speedup 1.0000x reference)
//
#include <hip/hip_runtime.h>
#include <hip/hip_bf16.h>
#include <cmath>

#define Bsz 2
#define Tsz 2048
#define Dsz 1024
#define Hn  8
#define DH  128
#define SCALE 0.08838834764831845f   // 1/sqrt(128)
#define SCL2  0.12753785246133148f   // SCALE * log2(e)

typedef __attribute__((ext_vector_type(8))) short short8;
typedef __attribute__((ext_vector_type(4))) short short4v;
typedef __attribute__((ext_vector_type(4))) float f32x4;
typedef __attribute__((ext_vector_type(16))) float f32x16;
typedef __attribute__((ext_vector_type(4))) unsigned int uint4v;
typedef __hip_bfloat16 bf16;

#define LDK 136  // flash K/V LDS row stride (128 + 8 pad)

__device__ __forceinline__ float bf2f(unsigned short u) {
    return __uint_as_float(((unsigned)u) << 16);
}
__device__ __forceinline__ unsigned short f2bf(float f) {
    bf16 h = __float2bfloat16(f);
    return *(unsigned short*)&h;
}
__device__ __forceinline__ unsigned pk2(float lo, float hi) {
    return (unsigned)f2bf(lo) | ((unsigned)f2bf(hi) << 16);
}
__device__ __forceinline__ short8 pack8(float4 a, float4 b) {
    short8 o;
    o[0] = (short)f2bf(a.x); o[1] = (short)f2bf(a.y);
    o[2] = (short)f2bf(a.z); o[3] = (short)f2bf(a.w);
    o[4] = (short)f2bf(b.x); o[5] = (short)f2bf(b.y);
    o[6] = (short)f2bf(b.z); o[7] = (short)f2bf(b.w);
    return o;
}

// async global->LDS, 16B per lane; lds dest = wave-uniform base + lane*16
__device__ __forceinline__ void gload16(const bf16* g, bf16* l) {
    __builtin_amdgcn_global_load_lds(
        (const __attribute__((address_space(1))) void*)g,
        (__attribute__((address_space(3))) void*)l, 16, 0, 0);
}

// ---------------------------------------------------------------------------
// fp32 -> bf16 conversion (weight matrices only)
// ---------------------------------------------------------------------------
struct CvtJob { const float* s; bf16* d; int n; };
struct CvtArgs { CvtJob j[4]; };

__global__ __launch_bounds__(256) void cvt_k(CvtArgs a) {
    CvtJob job = a.j[blockIdx.y];
    int idx = (blockIdx.x * 256 + threadIdx.x) * 8;
    const int stride = gridDim.x * 256 * 8;
    for (; idx < job.n; idx += stride) {
        float4 f0 = *(const float4*)(job.s + idx);
        float4 f1 = *(const float4*)(job.s + idx + 4);
        *(short8*)(job.d + idx) = pack8(f0, f1);
    }
}

// ---------------------------------------------------------------------------
// MFMA step over linear [128][32] LDS tiles (QKV GEMM)
// ---------------------------------------------------------------------------
__device__ __forceinline__ void mfma_step32(const bf16* As, const bf16* Bs,
                                            f32x4 acc[4][4],
                                            int wr, int wc, int fr, int g)
{
    short8 af[4], bfv[4];
#pragma unroll
    for (int m = 0; m < 4; ++m)
        af[m] = *(const short8*)(As + (wr * 64 + m * 16 + fr) * 32 + g * 8);
#pragma unroll
    for (int n = 0; n < 4; ++n)
        bfv[n] = *(const short8*)(Bs + (wc * 64 + n * 16 + fr) * 32 + g * 8);
#pragma unroll
    for (int m = 0; m < 4; ++m)
#pragma unroll
        for (int n = 0; n < 4; ++n)
            acc[m][n] = __builtin_amdgcn_mfma_f32_16x16x32_bf16(
                af[m], bfv[n], acc[m][n], 0, 0, 0);
}

// ---------------------------------------------------------------------------
// QKV projection GEMM: C = A(fp32) @ B(bf16)^T + bias. 1D grid 768, XCD-chunked.
// ---------------------------------------------------------------------------
struct GemmJob { const float* A; const bf16* B; const float* bias; void* C; int mode; };
struct GemmArgs { GemmJob j[3]; };

__global__ __launch_bounds__(256, 3) void gemm_qkv_k(GemmArgs args)
{
    __shared__ __align__(16) bf16 As[128 * 32];
    __shared__ __align__(16) bf16 Bs[128 * 32];
    const int bid = blockIdx.x;
    const int wid = (bid & 7) * 96 + (bid >> 3);   // T1: XCD-chunked
    const GemmJob job = args.j[wid >> 8];
    const int t = wid & 255;
    const int row0 = (t >> 3) * 128;
    const int col0 = (t & 7) * 128;
    const int tid = threadIdx.x;
    const int lane = tid & 63;
    const int w = tid >> 6, wr = w >> 1, wc = w & 1;
    const int fr = lane & 15, g = lane >> 4;

    const int srow = lane >> 2, scol = (lane & 3) * 8;
    const float* Ag0 = job.A + (size_t)(row0 + w * 32 + srow) * Dsz + scol;
    const float* Ag1 = Ag0 + 16 * Dsz;
    const bf16*  Bg  = job.B + (size_t)(col0 + w * 32 + srow) * Dsz + scol;
    const int lofs = __builtin_amdgcn_readfirstlane(w * 1024);
    bf16* Bsw = Bs + lofs;
    bf16* Aw0 = As + lofs + lane * 8;
    bf16* Aw1 = Aw0 + 16 * 32;

    f32x4 acc[4][4];
    const f32x4 vz = {0.f, 0.f, 0.f, 0.f};
#pragma unroll
    for (int m = 0; m < 4; ++m)
#pragma unroll
        for (int n = 0; n < 4; ++n) acc[m][n] = vz;

    float4 fa0 = *(const float4*)(Ag0);
    float4 fa1 = *(const float4*)(Ag0 + 4);
    float4 fa2 = *(const float4*)(Ag1);
    float4 fa3 = *(const float4*)(Ag1 + 4);

#pragma unroll 1
    for (int k0 = 0; k0 < Dsz; k0 += 32) {
        __syncthreads();
        *(short8*)Aw0 = pack8(fa0, fa1);
        *(short8*)Aw1 = pack8(fa2, fa3);
        gload16(Bg + k0, Bsw);
        gload16(Bg + 16 * Dsz + k0, Bsw + 16 * 32);
        __syncthreads();
        if (k0 + 32 < Dsz) {
            fa0 = *(const float4*)(Ag0 + k0 + 32);
            fa1 = *(const float4*)(Ag0 + k0 + 36);
            fa2 = *(const float4*)(Ag1 + k0 + 32);
            fa3 = *(const float4*)(Ag1 + k0 + 36);
        }
        mfma_step32(As, Bs, acc, wr, wc, fr, g);
    }

    if (job.mode == 2) {
        bf16* vtp = (bf16*)job.C;
#pragma unroll
        for (int m = 0; m < 4; ++m) {
            const int gi0 = row0 + wr * 64 + m * 16 + g * 4;
            const int bidx = gi0 >> 11, jj = gi0 & 2047;
#pragma unroll
            for (int n = 0; n < 4; ++n) {
                const int gj = col0 + wc * 64 + n * 16 + fr;
                const float bv = job.bias[gj];
                short4v pk;
#pragma unroll
                for (int r = 0; r < 4; ++r)
                    pk[r] = (short)f2bf(acc[m][n][r] + bv);
                const size_t zrow = ((size_t)bidx * 8 + (gj >> 7)) * 128 + (gj & 127);
                *(short4v*)(vtp + zrow * Tsz + jj) = pk;
            }
        }
    } else {
#pragma unroll
        for (int m = 0; m < 4; ++m) {
#pragma unroll
            for (int r = 0; r < 4; ++r) {
                const int gi = row0 + wr * 64 + m * 16 + g * 4 + r;
#pragma unroll
                for (int n = 0; n < 4; ++n) {
                    const int gj = col0 + wc * 64 + n * 16 + fr;
                    float x = acc[m][n][r] + job.bias[gj];
                    ((bf16*)job.C)[(size_t)gi * Dsz + gj] = __float2bfloat16(x);
                }
            }
        }
    }
}

// ---------------------------------------------------------------------------
// relpos projection
// ---------------------------------------------------------------------------
__global__ __launch_bounds__(256) void relproj_k(
    const bf16* __restrict__ tq, const float* __restrict__ table,
    float* __restrict__ proj)
{
    const int row  = blockIdx.x * 4 + (threadIdx.x >> 6);
    const int lane = threadIdx.x & 63;
    const bf16* qrow = tq + (size_t)row * Dsz;
    float acc[5] = {0.f, 0.f, 0.f, 0.f, 0.f};
#pragma unroll
    for (int t = 0; t < 4; ++t) {
        const int d = t * 256 + lane * 4;
        short4v q4 = *(const short4v*)(qrow + d);
        float qv[4];
#pragma unroll
        for (int q = 0; q < 4; ++q) qv[q] = bf2f((unsigned short)q4[q]);
#pragma unroll
        for (int c = 0; c < 5; ++c) {
            float4 t4 = *(const float4*)(table + c * Dsz + d);
            acc[c] = fmaf(qv[0], t4.x, acc[c]);
            acc[c] = fmaf(qv[1], t4.y, acc[c]);
            acc[c] = fmaf(qv[2], t4.z, acc[c]);
            acc[c] = fmaf(qv[3], t4.w, acc[c]);
        }
    }
#pragma unroll
    for (int c = 0; c < 5; ++c)
        for (int off = 32; off > 0; off >>= 1)
            acc[c] += __shfl_xor(acc[c], off);
    if (lane == 0) {
#pragma unroll
        for (int c = 0; c < 5; ++c)
            proj[(size_t)row * 8 + c] = acc[c];
    }
}

// ---------------------------------------------------------------------------
// Flash fused attention, 32x32x16 MFMA, P fully in registers (no Ps LDS).
// exp path in exp2 form: p = exp2(as*SCL2 + bias2), proj_s prescaled by SCL2.
// ---------------------------------------------------------------------------
__global__ __launch_bounds__(512) void flash_pv_k(
    const bf16* __restrict__ tq, const bf16* __restrict__ tk,
    const bf16* __restrict__ vt, const float* __restrict__ proj,
    float* __restrict__ invs_g, bf16* __restrict__ ctx)
{
    __shared__ __align__(16) char smem[2 * 128 * LDK * 2];   // Ks|Vs, reused as scratch
    __shared__ float proj_s[5 * 132];
    __shared__ float sums_l[8 * 32];
    bf16* Ks = (bf16*)smem;
    bf16* Vs = Ks + 128 * LDK;
    float* scratch = (float*)smem;

    const int tid = threadIdx.x;
    const int bid = blockIdx.x;
    const int wid = (bid & 7) * 32 + (bid >> 3);   // T1: 2 z per XCD
    const int qt = wid & 15, z = wid >> 4;
    const int b = z >> 3, h = z & 7;
    const int i0 = qt * 128;
    const int lane = tid & 63, w = tid >> 6;
    const int il = lane & 31, hi = lane >> 5;
    const int ig = w & 3, jh = w >> 2;
    const int i_local = ig * 32 + il;
    const int srow = tid >> 2, scb = (tid & 3) * 32;

    if (tid < 128) {
        const float* pr = proj + (size_t)(b * Tsz + i0 + tid) * 8;
#pragma unroll
        for (int c = 0; c < 5; ++c) proj_s[c * 132 + tid] = pr[c] * SCL2;
    }

    const bf16* qrow = tq + (size_t)(b * Tsz + i0 + i_local) * Dsz + h * DH + hi * 8;
    short8 qf[8];
#pragma unroll
    for (int kc = 0; kc < 8; ++kc)
        qf[kc] = *(const short8*)(qrow + kc * 16);

    f32x16 accp[4];
#pragma unroll
    for (int d4 = 0; d4 < 4; ++d4)
#pragma unroll
        for (int e = 0; e < 16; ++e) accp[d4][e] = 0.f;
    float rs = 0.f;

    const bf16* kg = tk + (size_t)(b * Tsz + srow) * Dsz + h * DH + scb;
    const bf16* vg = vt + ((size_t)z * DH + srow) * Tsz + scb;
    short8 kv[4], vv[4];
#pragma unroll
    for (int q = 0; q < 4; ++q) kv[q] = *(const short8*)(kg + q * 8);
#pragma unroll
    for (int q = 0; q < 4; ++q) vv[q] = *(const short8*)(vg + q * 8);

#pragma unroll 1
    for (int kt = 0; kt < Tsz / 128; ++kt) {
        __syncthreads();
#pragma unroll
        for (int q = 0; q < 4; ++q) *(short8*)(Ks + srow * LDK + scb + q * 8) = kv[q];
#pragma unroll
        for (int q = 0; q < 4; ++q) *(short8*)(Vs + srow * LDK + scb + q * 8) = vv[q];
        __syncthreads();

        if (kt + 1 < Tsz / 128) {
            const bf16* kn = kg + (size_t)(kt + 1) * 128 * Dsz;
            const bf16* vn = vg + (kt + 1) * 128;
#pragma unroll
            for (int q = 0; q < 4; ++q) kv[q] = *(const short8*)(kn + q * 8);
#pragma unroll
            for (int q = 0; q < 4; ++q) vv[q] = *(const short8*)(vn + q * 8);
        }

        f32x16 as_[2];
#pragma unroll
        for (int jf = 0; jf < 2; ++jf)
#pragma unroll
            for (int e = 0; e < 16; ++e) as_[jf][e] = 0.f;
        __builtin_amdgcn_s_setprio(1);
#pragma unroll
        for (int kc = 0; kc < 8; ++kc) {
            short8 kf0 = *(const short8*)(Ks + (jh * 64 + il) * LDK + kc * 16 + hi * 8);
            short8 kf1 = *(const short8*)(Ks + (jh * 64 + 32 + il) * LDK + kc * 16 + hi * 8);
            as_[0] = __builtin_amdgcn_mfma_f32_32x32x16_bf16(kf0, qf[kc], as_[0], 0, 0, 0);
            as_[1] = __builtin_amdgcn_mfma_f32_32x32x16_bf16(kf1, qf[kc], as_[1], 0, 0, 0);
        }
        __builtin_amdgcn_s_setprio(0);

        const int dt = kt - qt;
        if (dt <= -2 || dt >= 2) {
            const float bias2 = proj_s[((dt >= 2) ? 4 : 0) * 132 + i_local];
#pragma unroll
            for (int jf = 0; jf < 2; ++jf)
#pragma unroll
                for (int e = 0; e < 16; ++e) {
                    float p = exp2f(fmaf(as_[jf][e], SCL2, bias2));
                    rs += p;
                    as_[jf][e] = p;
                }
        } else {
#pragma unroll
            for (int jf = 0; jf < 2; ++jf)
#pragma unroll
                for (int e = 0; e < 16; ++e) {
                    const int jloc = jh * 64 + jf * 32 + (e & 3) + 8 * (e >> 2) + 4 * hi;
                    int dd = (jloc + dt * 128) - i_local;
                    dd = dd < -2 ? -2 : (dd > 2 ? 2 : dd);
                    const float bias2 = proj_s[(dd + 2) * 132 + i_local];
                    float p = exp2f(fmaf(as_[jf][e], SCL2, bias2));
                    rs += p;
                    as_[jf][e] = p;
                }
        }

        unsigned pw[2][8];
#pragma unroll
        for (int jf = 0; jf < 2; ++jf)
#pragma unroll
            for (int q = 0; q < 8; ++q)
                pw[jf][q] = pk2(as_[jf][2 * q], as_[jf][2 * q + 1]);

        __builtin_amdgcn_s_setprio(1);
#pragma unroll
        for (int chunk = 0; chunk < 4; ++chunk) {
            const int jf = chunk >> 1;
            const int c2 = (chunk & 1) * 2;
            unsigned W0a = pw[jf][c2 * 2],       W0b = pw[jf][c2 * 2 + 1];
            unsigned W1a = pw[jf][(c2 + 1) * 2], W1b = pw[jf][(c2 + 1) * 2 + 1];
            unsigned X0a = __shfl_xor((int)W0a, 32), X0b = __shfl_xor((int)W0b, 32);
            unsigned X1a = __shfl_xor((int)W1a, 32), X1b = __shfl_xor((int)W1b, 32);
            uint4v u;
            u[0] = hi == 0 ? W0a : X1a;
            u[1] = hi == 0 ? W0b : X1b;
            u[2] = hi == 0 ? X0a : W1a;
            u[3] = hi == 0 ? X0b : W1b;
            short8 pb = *(short8*)&u;
            const int jcol = jh * 64 + chunk * 16 + hi * 8;
#pragma unroll
            for (int d4 = 0; d4 < 4; ++d4) {
                short8 vtf = *(const short8*)(Vs + (d4 * 32 + il) * LDK + jcol);
                accp[d4] = __builtin_amdgcn_mfma_f32_32x32x16_bf16(vtf, pb, accp[d4], 0, 0, 0);
            }
        }
        __builtin_amdgcn_s_setprio(0);
    }

    rs += __shfl_xor(rs, 32);
    if (lane < 32) sums_l[w * 32 + il] = rs;
    __syncthreads();
    const float total = sums_l[ig * 32 + il] + sums_l[(ig + 4) * 32 + il];
    const float iv = 1.0f / total;
    if (jh == 0 && hi == 0)
        invs_g[(size_t)z * Tsz + i0 + i_local] = iv;

    if (jh == 1) {
#pragma unroll
        for (int d4 = 0; d4 < 4; ++d4)
#pragma unroll
            for (int e = 0; e < 16; ++e)
                scratch[((ig * 4 + d4) * 16 + e) * 64 + lane] = accp[d4][e];
    }
    __syncthreads();
    if (jh == 0) {
        bf16* cp = ctx + (size_t)(b * Tsz + i0 + i_local) * Dsz + h * DH;
#pragma unroll
        for (int d4 = 0; d4 < 4; ++d4)
#pragma unroll
            for (int e = 0; e < 16; ++e) {
                float v = accp[d4][e] + scratch[((ig * 4 + d4) * 16 + e) * 64 + lane];
                const int d = d4 * 32 + (e & 3) + 8 * (e >> 2) + 4 * hi;
                cp[d] = __float2bfloat16(v * iv);
            }
    }
}

// ---------------------------------------------------------------------------
// Merged weights + output-projection kernel (256^2 tiles, NT stores).
// Weights epilogue in exp2 form: w = exp2(acc*SCL2 + (bias*SCL2 + log2(iv)))
// -> 1 fma + 1 exp per element (proj_s prescaled, inv_s holds log2(iv)).
// ---------------------------------------------------------------------------
__global__ __launch_bounds__(512) void wo_k(
    const bf16* __restrict__ tq, const bf16* __restrict__ tk,
    const float* __restrict__ proj, const float* __restrict__ invs_g,
    float* __restrict__ Wt,
    const bf16* __restrict__ ctx, const bf16* __restrict__ Wob,
    const float* __restrict__ bo, float* __restrict__ out)
{
    __shared__ __align__(16) bf16 As[256 * 32];
    __shared__ __align__(16) bf16 Bs[256 * 32];
    __shared__ float proj_s[5 * 264];
    __shared__ float inv_s[256];

    const int tid = threadIdx.x;
    const int lane = tid & 63, w = tid >> 6;
    const int fr = lane & 15, g = lane >> 4;
    const int wj = w & 3, wi = w >> 2;            // j-quarter / i-half
    const int srow = lane >> 2, scol = (lane & 3) * 8;
    const int lofs = __builtin_amdgcn_readfirstlane(w * 1024);  // 32 rows/wave
    bf16* Asw = As + lofs;
    bf16* Bsw = Bs + lofs;
    const f32x4 vz = {0.f, 0.f, 0.f, 0.f};
    const int bid = blockIdx.x;

    if (bid >= 64) {
        const int b0 = bid - 64;
        const int wid = (b0 & 7) * 128 + (b0 >> 3);   // T1: 2 z per XCD
        const int z = wid >> 6;
        const int t = wid & 63;
        const int row0 = (t >> 3) * 256;   // i
        const int col0 = (t & 7) * 256;    // j
        const int b = z >> 3, h = z & 7;

        if (tid < 256) {
            const float* pr = proj + (size_t)(b * Tsz + row0 + tid) * 8;
#pragma unroll
            for (int c = 0; c < 5; ++c) proj_s[c * 264 + tid] = pr[c] * SCL2;
        } else {
            inv_s[tid - 256] = log2f(invs_g[(size_t)z * Tsz + row0 + (tid - 256)]);
        }

        const bf16* Ag = tk + (size_t)(b * Tsz + col0 + w * 32 + srow) * Dsz + h * DH + scol;
        const bf16* Bg = tq + (size_t)(b * Tsz + row0 + w * 32 + srow) * Dsz + h * DH + scol;

        f32x4 acc[4][8];   // [jf][ii]
#pragma unroll
        for (int m = 0; m < 4; ++m)
#pragma unroll
            for (int n = 0; n < 8; ++n) acc[m][n] = vz;

#pragma unroll 1
        for (int k0 = 0; k0 < DH; k0 += 32) {
            __syncthreads();
            gload16(Ag + k0, Asw);
            gload16(Ag + 16 * Dsz + k0, Asw + 16 * 32);
            gload16(Bg + k0, Bsw);
            gload16(Bg + 16 * Dsz + k0, Bsw + 16 * 32);
            __syncthreads();
            short8 af[4], bfv[8];
#pragma unroll
            for (int jf = 0; jf < 4; ++jf)
                af[jf] = *(const short8*)(As + (wj * 64 + jf * 16 + fr) * 32 + g * 8);
#pragma unroll
            for (int ii = 0; ii < 8; ++ii)
                bfv[ii] = *(const short8*)(Bs + (wi * 128 + ii * 16 + fr) * 32 + g * 8);
#pragma unroll
            for (int jf = 0; jf < 4; ++jf)
#pragma unroll
                for (int ii = 0; ii < 8; ++ii)
                    acc[jf][ii] = __builtin_amdgcn_mfma_f32_16x16x32_bf16(
                        af[jf], bfv[ii], acc[jf][ii], 0, 0, 0);
        }

        float* C = Wt + (size_t)z * Tsz * Tsz;
        const int dmin = col0 - (row0 + 255);
        const int dmax = (col0 + 255) - row0;
        if (dmin >= 2 || dmax <= -2) {
            const int c = (dmin >= 2) ? 4 : 0;
#pragma unroll
            for (int ii = 0; ii < 8; ++ii) {
                const int il = wi * 128 + ii * 16 + fr;
                const int gi = row0 + il;
                const float cb = proj_s[c * 264 + il] + inv_s[il];
#pragma unroll
                for (int jf = 0; jf < 4; ++jf) {
                    const int jb = col0 + wj * 64 + jf * 16 + g * 4;
                    f32x4 o;
#pragma unroll
                    for (int r = 0; r < 4; ++r)
                        o[r] = exp2f(fmaf(acc[jf][ii][r], SCL2, cb));
                    __builtin_nontemporal_store(o, (f32x4*)(C + (size_t)gi * Tsz + jb));
                }
            }
        } else {
#pragma unroll
            for (int ii = 0; ii < 8; ++ii) {
                const int il = wi * 128 + ii * 16 + fr;
                const int gi = row0 + il;
                const float liv = inv_s[il];
#pragma unroll
                for (int jf = 0; jf < 4; ++jf) {
                    const int jb = col0 + wj * 64 + jf * 16 + g * 4;
                    f32x4 o;
#pragma unroll
                    for (int r = 0; r < 4; ++r) {
                        int rel = (jb + r) - gi;
                        rel = rel < -2 ? -2 : (rel > 2 ? 2 : rel);
                        const float cb = proj_s[(rel + 2) * 264 + il] + liv;
                        o[r] = exp2f(fmaf(acc[jf][ii][r], SCL2, cb));
                    }
                    __builtin_nontemporal_store(o, (f32x4*)(C + (size_t)gi * Tsz + jb));
                }
            }
        }
    } else {
        const int row0 = (bid >> 2) * 256;   // i (16 tiles)
        const int col0 = (bid & 3) * 256;    // out col (4 tiles)
        const bf16* Ag = ctx + (size_t)(row0 + w * 32 + srow) * Dsz + scol;
        const bf16* Bg = Wob + (size_t)(col0 + w * 32 + srow) * Dsz + scol;

        f32x4 acc2[8][4];  // [ii][jc]
#pragma unroll
        for (int m = 0; m < 8; ++m)
#pragma unroll
            for (int n = 0; n < 4; ++n) acc2[m][n] = vz;

#pragma unroll 1
        for (int k0 = 0; k0 < Dsz; k0 += 32) {
            __syncthreads();
            gload16(Ag + k0, Asw);
            gload16(Ag + 16 * Dsz + k0, Asw + 16 * 32);
            gload16(Bg + k0, Bsw);
            gload16(Bg + 16 * Dsz + k0, Bsw + 16 * 32);
            __syncthreads();
            short8 af[8], bfv[4];
#pragma unroll
            for (int ii = 0; ii < 8; ++ii)
                af[ii] = *(const short8*)(As + (wi * 128 + ii * 16 + fr) * 32 + g * 8);
#pragma unroll
            for (int jc = 0; jc < 4; ++jc)
                bfv[jc] = *(const short8*)(Bs + (wj * 64 + jc * 16 + fr) * 32 + g * 8);
#pragma unroll
            for (int ii = 0; ii < 8; ++ii)
#pragma unroll
                for (int jc = 0; jc < 4; ++jc)
                    acc2[ii][jc] = __builtin_amdgcn_mfma_f32_16x16x32_bf16(
                        af[ii], bfv[jc], acc2[ii][jc], 0, 0, 0);
        }

#pragma unroll
        for (int ii = 0; ii < 8; ++ii) {
#pragma unroll
            for (int r = 0; r < 4; ++r) {
                const int gi = row0 + wi * 128 + ii * 16 + g * 4 + r;
#pragma unroll
                for (int jc = 0; jc < 4; ++jc) {
                    const int gj = col0 + wj * 64 + jc * 16 + fr;
                    out[(size_t)gi * Dsz + gj] = acc2[ii][jc][r] + bo[gj];
                }
            }
        }
    }
}

// ---------------------------------------------------------------------------
extern "C" void kernel_launch(void* const* d_in, const int* in_sizes, int n_in,
                              void* d_out, int out_size, void* d_ws, size_t ws_size,
                              hipStream_t stream)
{
    const float* query  = (const float*)d_in[0];
    const float* keys   = (const float*)d_in[1];
    const float* values = (const float*)d_in[2];
    const float* Wq = (const float*)d_in[3];
    const float* bq = (const float*)d_in[4];
    const float* Wk = (const float*)d_in[5];
    const float* bk = (const float*)d_in[6];
    const float* Wv = (const float*)d_in[7];
    const float* bv = (const float*)d_in[8];
    const float* Wo = (const float*)d_in[9];
    const float* bo = (const float*)d_in[10];
    const float* table = (const float*)d_in[11];

    float* out     = (float*)d_out;                      // B*T*D fp32
    float* weights = out + (size_t)Bsz * Tsz * Dsz;      // B*H*T*T fp32

    char* wp = (char*)d_ws;
    bf16* tq  = (bf16*)(wp);
    bf16* tk  = (bf16*)(wp + 8  * 1024 * 1024);
    bf16* vt  = (bf16*)(wp + 16 * 1024 * 1024);          // V in [z][d][j] layout
    bf16* ctx = (bf16*)(wp + 24 * 1024 * 1024);
    bf16* Wqb = (bf16*)(wp + 32 * 1024 * 1024);
    bf16* Wkb = (bf16*)(wp + 34 * 1024 * 1024);
    bf16* Wvb = (bf16*)(wp + 36 * 1024 * 1024);
    bf16* Wob = (bf16*)(wp + 38 * 1024 * 1024);
    float* proj   = (float*)(wp + 40 * 1024 * 1024);
    float* invs_g = (float*)(wp + 41 * 1024 * 1024);

    const dim3 blk(256);

    CvtArgs ca;
    ca.j[0] = { Wq, Wqb, Dsz * Dsz };
    ca.j[1] = { Wk, Wkb, Dsz * Dsz };
    ca.j[2] = { Wv, Wvb, Dsz * Dsz };
    ca.j[3] = { Wo, Wob, Dsz * Dsz };
    cvt_k<<<dim3(128, 4), blk, 0, stream>>>(ca);

    GemmArgs ga;
    ga.j[0] = { query,  Wqb, bq, tq, 1 };
    ga.j[1] = { keys,   Wkb, bk, tk, 1 };
    ga.j[2] = { values, Wvb, bv, vt, 2 };
    gemm_qkv_k<<<dim3(768), blk, 0, stream>>>(ga);

    relproj_k<<<dim3(Bsz * Tsz / 4), blk, 0, stream>>>(tq, table, proj);

    flash_pv_k<<<dim3(256), dim3(512), 0, stream>>>(
        tq, tk, vt, proj, invs_g, ctx);

    wo_k<<<dim3(64 + 1024), dim3(512), 0, stream>>>(
        tq, tk, proj, invs_g, weights, ctx, Wob, bo, out);
}

// Round 23
// 185.922 us; speedup vs baseline: 1.0403x; 1.0403x over previous
//
#include <hip/hip_runtime.h>
#include <hip/hip_bf16.h>
#include <cmath>

#define Bsz 2
#define Tsz 2048
#define Dsz 1024
#define Hn  8
#define DH  128
#define SCALE 0.08838834764831845f   // 1/sqrt(128)
#define SCL2  0.12753785246133148f   // SCALE * log2(e)

typedef __attribute__((ext_vector_type(8))) short short8;
typedef __attribute__((ext_vector_type(4))) short short4v;
typedef __attribute__((ext_vector_type(4))) float f32x4;
typedef __attribute__((ext_vector_type(16))) float f32x16;
typedef __attribute__((ext_vector_type(4))) unsigned int uint4v;
typedef __hip_bfloat16 bf16;

#define LDK 136  // flash K/V LDS row stride (128 + 8 pad)

__device__ __forceinline__ float bf2f(unsigned short u) {
    return __uint_as_float(((unsigned)u) << 16);
}
__device__ __forceinline__ unsigned short f2bf(float f) {
    bf16 h = __float2bfloat16(f);
    return *(unsigned short*)&h;
}
__device__ __forceinline__ unsigned pk2(float lo, float hi) {
    return (unsigned)f2bf(lo) | ((unsigned)f2bf(hi) << 16);
}
__device__ __forceinline__ float fexp2(float x) {
    return __builtin_amdgcn_exp2f(x);   // raw v_exp_f32 (D = 2^S0)
}
__device__ __forceinline__ short8 pack8(float4 a, float4 b) {
    short8 o;
    o[0] = (short)f2bf(a.x); o[1] = (short)f2bf(a.y);
    o[2] = (short)f2bf(a.z); o[3] = (short)f2bf(a.w);
    o[4] = (short)f2bf(b.x); o[5] = (short)f2bf(b.y);
    o[6] = (short)f2bf(b.z); o[7] = (short)f2bf(b.w);
    return o;
}

// async global->LDS, 16B per lane; lds dest = wave-uniform base + lane*16
__device__ __forceinline__ void gload16(const bf16* g, bf16* l) {
    __builtin_amdgcn_global_load_lds(
        (const __attribute__((address_space(1))) void*)g,
        (__attribute__((address_space(3))) void*)l, 16, 0, 0);
}

// ---------------------------------------------------------------------------
// fp32 -> bf16 conversion (weight matrices only)
// ---------------------------------------------------------------------------
struct CvtJob { const float* s; bf16* d; int n; };
struct CvtArgs { CvtJob j[4]; };

__global__ __launch_bounds__(256) void cvt_k(CvtArgs a) {
    CvtJob job = a.j[blockIdx.y];
    int idx = (blockIdx.x * 256 + threadIdx.x) * 8;
    const int stride = gridDim.x * 256 * 8;
    for (; idx < job.n; idx += stride) {
        float4 f0 = *(const float4*)(job.s + idx);
        float4 f1 = *(const float4*)(job.s + idx + 4);
        *(short8*)(job.d + idx) = pack8(f0, f1);
    }
}

// ---------------------------------------------------------------------------
// MFMA step over linear [128][32] LDS tiles (QKV GEMM)
// ---------------------------------------------------------------------------
__device__ __forceinline__ void mfma_step32(const bf16* As, const bf16* Bs,
                                            f32x4 acc[4][4],
                                            int wr, int wc, int fr, int g)
{
    short8 af[4], bfv[4];
#pragma unroll
    for (int m = 0; m < 4; ++m)
        af[m] = *(const short8*)(As + (wr * 64 + m * 16 + fr) * 32 + g * 8);
#pragma unroll
    for (int n = 0; n < 4; ++n)
        bfv[n] = *(const short8*)(Bs + (wc * 64 + n * 16 + fr) * 32 + g * 8);
#pragma unroll
    for (int m = 0; m < 4; ++m)
#pragma unroll
        for (int n = 0; n < 4; ++n)
            acc[m][n] = __builtin_amdgcn_mfma_f32_16x16x32_bf16(
                af[m], bfv[n], acc[m][n], 0, 0, 0);
}

// ---------------------------------------------------------------------------
// QKV projection GEMM: C = A(fp32) @ B(bf16)^T + bias. 1D grid 768, XCD-chunked.
// ---------------------------------------------------------------------------
struct GemmJob { const float* A; const bf16* B; const float* bias; void* C; int mode; };
struct GemmArgs { GemmJob j[3]; };

__global__ __launch_bounds__(256, 3) void gemm_qkv_k(GemmArgs args)
{
    __shared__ __align__(16) bf16 As[128 * 32];
    __shared__ __align__(16) bf16 Bs[128 * 32];
    const int bid = blockIdx.x;
    const int wid = (bid & 7) * 96 + (bid >> 3);   // T1: XCD-chunked
    const GemmJob job = args.j[wid >> 8];
    const int t = wid & 255;
    const int row0 = (t >> 3) * 128;
    const int col0 = (t & 7) * 128;
    const int tid = threadIdx.x;
    const int lane = tid & 63;
    const int w = tid >> 6, wr = w >> 1, wc = w & 1;
    const int fr = lane & 15, g = lane >> 4;

    const int srow = lane >> 2, scol = (lane & 3) * 8;
    const float* Ag0 = job.A + (size_t)(row0 + w * 32 + srow) * Dsz + scol;
    const float* Ag1 = Ag0 + 16 * Dsz;
    const bf16*  Bg  = job.B + (size_t)(col0 + w * 32 + srow) * Dsz + scol;
    const int lofs = __builtin_amdgcn_readfirstlane(w * 1024);
    bf16* Bsw = Bs + lofs;
    bf16* Aw0 = As + lofs + lane * 8;
    bf16* Aw1 = Aw0 + 16 * 32;

    f32x4 acc[4][4];
    const f32x4 vz = {0.f, 0.f, 0.f, 0.f};
#pragma unroll
    for (int m = 0; m < 4; ++m)
#pragma unroll
        for (int n = 0; n < 4; ++n) acc[m][n] = vz;

    float4 fa0 = *(const float4*)(Ag0);
    float4 fa1 = *(const float4*)(Ag0 + 4);
    float4 fa2 = *(const float4*)(Ag1);
    float4 fa3 = *(const float4*)(Ag1 + 4);

#pragma unroll 1
    for (int k0 = 0; k0 < Dsz; k0 += 32) {
        __syncthreads();
        *(short8*)Aw0 = pack8(fa0, fa1);
        *(short8*)Aw1 = pack8(fa2, fa3);
        gload16(Bg + k0, Bsw);
        gload16(Bg + 16 * Dsz + k0, Bsw + 16 * 32);
        __syncthreads();
        if (k0 + 32 < Dsz) {
            fa0 = *(const float4*)(Ag0 + k0 + 32);
            fa1 = *(const float4*)(Ag0 + k0 + 36);
            fa2 = *(const float4*)(Ag1 + k0 + 32);
            fa3 = *(const float4*)(Ag1 + k0 + 36);
        }
        mfma_step32(As, Bs, acc, wr, wc, fr, g);
    }

    if (job.mode == 2) {
        bf16* vtp = (bf16*)job.C;
#pragma unroll
        for (int m = 0; m < 4; ++m) {
            const int gi0 = row0 + wr * 64 + m * 16 + g * 4;
            const int bidx = gi0 >> 11, jj = gi0 & 2047;
#pragma unroll
            for (int n = 0; n < 4; ++n) {
                const int gj = col0 + wc * 64 + n * 16 + fr;
                const float bv = job.bias[gj];
                short4v pk;
#pragma unroll
                for (int r = 0; r < 4; ++r)
                    pk[r] = (short)f2bf(acc[m][n][r] + bv);
                const size_t zrow = ((size_t)bidx * 8 + (gj >> 7)) * 128 + (gj & 127);
                *(short4v*)(vtp + zrow * Tsz + jj) = pk;
            }
        }
    } else {
#pragma unroll
        for (int m = 0; m < 4; ++m) {
#pragma unroll
            for (int r = 0; r < 4; ++r) {
                const int gi = row0 + wr * 64 + m * 16 + g * 4 + r;
#pragma unroll
                for (int n = 0; n < 4; ++n) {
                    const int gj = col0 + wc * 64 + n * 16 + fr;
                    float x = acc[m][n][r] + job.bias[gj];
                    ((bf16*)job.C)[(size_t)gi * Dsz + gj] = __float2bfloat16(x);
                }
            }
        }
    }
}

// ---------------------------------------------------------------------------
// relpos projection
// ---------------------------------------------------------------------------
__global__ __launch_bounds__(256) void relproj_k(
    const bf16* __restrict__ tq, const float* __restrict__ table,
    float* __restrict__ proj)
{
    const int row  = blockIdx.x * 4 + (threadIdx.x >> 6);
    const int lane = threadIdx.x & 63;
    const bf16* qrow = tq + (size_t)row * Dsz;
    float acc[5] = {0.f, 0.f, 0.f, 0.f, 0.f};
#pragma unroll
    for (int t = 0; t < 4; ++t) {
        const int d = t * 256 + lane * 4;
        short4v q4 = *(const short4v*)(qrow + d);
        float qv[4];
#pragma unroll
        for (int q = 0; q < 4; ++q) qv[q] = bf2f((unsigned short)q4[q]);
#pragma unroll
        for (int c = 0; c < 5; ++c) {
            float4 t4 = *(const float4*)(table + c * Dsz + d);
            acc[c] = fmaf(qv[0], t4.x, acc[c]);
            acc[c] = fmaf(qv[1], t4.y, acc[c]);
            acc[c] = fmaf(qv[2], t4.z, acc[c]);
            acc[c] = fmaf(qv[3], t4.w, acc[c]);
        }
    }
#pragma unroll
    for (int c = 0; c < 5; ++c)
        for (int off = 32; off > 0; off >>= 1)
            acc[c] += __shfl_xor(acc[c], off);
    if (lane == 0) {
#pragma unroll
        for (int c = 0; c < 5; ++c)
            proj[(size_t)row * 8 + c] = acc[c];
    }
}

// ---------------------------------------------------------------------------
// Flash fused attention, 32x32x16 MFMA, P fully in registers (no Ps LDS).
// exp path: p = v_exp_f32(as*SCL2 + bias2), proj_s prescaled by SCL2.
// ---------------------------------------------------------------------------
__global__ __launch_bounds__(512) void flash_pv_k(
    const bf16* __restrict__ tq, const bf16* __restrict__ tk,
    const bf16* __restrict__ vt, const float* __restrict__ proj,
    float* __restrict__ invs_g, bf16* __restrict__ ctx)
{
    __shared__ __align__(16) char smem[2 * 128 * LDK * 2];   // Ks|Vs, reused as scratch
    __shared__ float proj_s[5 * 132];
    __shared__ float sums_l[8 * 32];
    bf16* Ks = (bf16*)smem;
    bf16* Vs = Ks + 128 * LDK;
    float* scratch = (float*)smem;

    const int tid = threadIdx.x;
    const int bid = blockIdx.x;
    const int wid = (bid & 7) * 32 + (bid >> 3);   // T1: 2 z per XCD
    const int qt = wid & 15, z = wid >> 4;
    const int b = z >> 3, h = z & 7;
    const int i0 = qt * 128;
    const int lane = tid & 63, w = tid >> 6;
    const int il = lane & 31, hi = lane >> 5;
    const int ig = w & 3, jh = w >> 2;
    const int i_local = ig * 32 + il;
    const int srow = tid >> 2, scb = (tid & 3) * 32;

    if (tid < 128) {
        const float* pr = proj + (size_t)(b * Tsz + i0 + tid) * 8;
#pragma unroll
        for (int c = 0; c < 5; ++c) proj_s[c * 132 + tid] = pr[c] * SCL2;
    }

    const bf16* qrow = tq + (size_t)(b * Tsz + i0 + i_local) * Dsz + h * DH + hi * 8;
    short8 qf[8];
#pragma unroll
    for (int kc = 0; kc < 8; ++kc)
        qf[kc] = *(const short8*)(qrow + kc * 16);

    f32x16 accp[4];
#pragma unroll
    for (int d4 = 0; d4 < 4; ++d4)
#pragma unroll
        for (int e = 0; e < 16; ++e) accp[d4][e] = 0.f;
    float rs = 0.f;

    const bf16* kg = tk + (size_t)(b * Tsz + srow) * Dsz + h * DH + scb;
    const bf16* vg = vt + ((size_t)z * DH + srow) * Tsz + scb;
    short8 kv[4], vv[4];
#pragma unroll
    for (int q = 0; q < 4; ++q) kv[q] = *(const short8*)(kg + q * 8);
#pragma unroll
    for (int q = 0; q < 4; ++q) vv[q] = *(const short8*)(vg + q * 8);

#pragma unroll 1
    for (int kt = 0; kt < Tsz / 128; ++kt) {
        __syncthreads();
#pragma unroll
        for (int q = 0; q < 4; ++q) *(short8*)(Ks + srow * LDK + scb + q * 8) = kv[q];
#pragma unroll
        for (int q = 0; q < 4; ++q) *(short8*)(Vs + srow * LDK + scb + q * 8) = vv[q];
        __syncthreads();

        if (kt + 1 < Tsz / 128) {
            const bf16* kn = kg + (size_t)(kt + 1) * 128 * Dsz;
            const bf16* vn = vg + (kt + 1) * 128;
#pragma unroll
            for (int q = 0; q < 4; ++q) kv[q] = *(const short8*)(kn + q * 8);
#pragma unroll
            for (int q = 0; q < 4; ++q) vv[q] = *(const short8*)(vn + q * 8);
        }

        f32x16 as_[2];
#pragma unroll
        for (int jf = 0; jf < 2; ++jf)
#pragma unroll
            for (int e = 0; e < 16; ++e) as_[jf][e] = 0.f;
        __builtin_amdgcn_s_setprio(1);
#pragma unroll
        for (int kc = 0; kc < 8; ++kc) {
            short8 kf0 = *(const short8*)(Ks + (jh * 64 + il) * LDK + kc * 16 + hi * 8);
            short8 kf1 = *(const short8*)(Ks + (jh * 64 + 32 + il) * LDK + kc * 16 + hi * 8);
            as_[0] = __builtin_amdgcn_mfma_f32_32x32x16_bf16(kf0, qf[kc], as_[0], 0, 0, 0);
            as_[1] = __builtin_amdgcn_mfma_f32_32x32x16_bf16(kf1, qf[kc], as_[1], 0, 0, 0);
        }
        __builtin_amdgcn_s_setprio(0);

        const int dt = kt - qt;
        if (dt <= -2 || dt >= 2) {
            const float bias2 = proj_s[((dt >= 2) ? 4 : 0) * 132 + i_local];
#pragma unroll
            for (int jf = 0; jf < 2; ++jf)
#pragma unroll
                for (int e = 0; e < 16; ++e) {
                    float p = fexp2(fmaf(as_[jf][e], SCL2, bias2));
                    rs += p;
                    as_[jf][e] = p;
                }
        } else {
#pragma unroll
            for (int jf = 0; jf < 2; ++jf)
#pragma unroll
                for (int e = 0; e < 16; ++e) {
                    const int jloc = jh * 64 + jf * 32 + (e & 3) + 8 * (e >> 2) + 4 * hi;
                    int dd = (jloc + dt * 128) - i_local;
                    dd = dd < -2 ? -2 : (dd > 2 ? 2 : dd);
                    const float bias2 = proj_s[(dd + 2) * 132 + i_local];
                    float p = fexp2(fmaf(as_[jf][e], SCL2, bias2));
                    rs += p;
                    as_[jf][e] = p;
                }
        }

        unsigned pw[2][8];
#pragma unroll
        for (int jf = 0; jf < 2; ++jf)
#pragma unroll
            for (int q = 0; q < 8; ++q)
                pw[jf][q] = pk2(as_[jf][2 * q], as_[jf][2 * q + 1]);

        __builtin_amdgcn_s_setprio(1);
#pragma unroll
        for (int chunk = 0; chunk < 4; ++chunk) {
            const int jf = chunk >> 1;
            const int c2 = (chunk & 1) * 2;
            unsigned W0a = pw[jf][c2 * 2],       W0b = pw[jf][c2 * 2 + 1];
            unsigned W1a = pw[jf][(c2 + 1) * 2], W1b = pw[jf][(c2 + 1) * 2 + 1];
            unsigned X0a = __shfl_xor((int)W0a, 32), X0b = __shfl_xor((int)W0b, 32);
            unsigned X1a = __shfl_xor((int)W1a, 32), X1b = __shfl_xor((int)W1b, 32);
            uint4v u;
            u[0] = hi == 0 ? W0a : X1a;
            u[1] = hi == 0 ? W0b : X1b;
            u[2] = hi == 0 ? X0a : W1a;
            u[3] = hi == 0 ? X0b : W1b;
            short8 pb = *(short8*)&u;
            const int jcol = jh * 64 + chunk * 16 + hi * 8;
#pragma unroll
            for (int d4 = 0; d4 < 4; ++d4) {
                short8 vtf = *(const short8*)(Vs + (d4 * 32 + il) * LDK + jcol);
                accp[d4] = __builtin_amdgcn_mfma_f32_32x32x16_bf16(vtf, pb, accp[d4], 0, 0, 0);
            }
        }
        __builtin_amdgcn_s_setprio(0);
    }

    rs += __shfl_xor(rs, 32);
    if (lane < 32) sums_l[w * 32 + il] = rs;
    __syncthreads();
    const float total = sums_l[ig * 32 + il] + sums_l[(ig + 4) * 32 + il];
    const float iv = 1.0f / total;
    if (jh == 0 && hi == 0)
        invs_g[(size_t)z * Tsz + i0 + i_local] = iv;

    if (jh == 1) {
#pragma unroll
        for (int d4 = 0; d4 < 4; ++d4)
#pragma unroll
            for (int e = 0; e < 16; ++e)
                scratch[((ig * 4 + d4) * 16 + e) * 64 + lane] = accp[d4][e];
    }
    __syncthreads();
    if (jh == 0) {
        bf16* cp = ctx + (size_t)(b * Tsz + i0 + i_local) * Dsz + h * DH;
#pragma unroll
        for (int d4 = 0; d4 < 4; ++d4)
#pragma unroll
            for (int e = 0; e < 16; ++e) {
                float v = accp[d4][e] + scratch[((ig * 4 + d4) * 16 + e) * 64 + lane];
                const int d = d4 * 32 + (e & 3) + 8 * (e >> 2) + 4 * hi;
                cp[d] = __float2bfloat16(v * iv);
            }
    }
}

// ---------------------------------------------------------------------------
// Merged weights + output-projection kernel (256^2 tiles, NT stores).
// Weights epilogue: w = v_exp_f32(acc*SCL2 + (bias*SCL2 + log2(iv)))
// ---------------------------------------------------------------------------
__global__ __launch_bounds__(512) void wo_k(
    const bf16* __restrict__ tq, const bf16* __restrict__ tk,
    const float* __restrict__ proj, const float* __restrict__ invs_g,
    float* __restrict__ Wt,
    const bf16* __restrict__ ctx, const bf16* __restrict__ Wob,
    const float* __restrict__ bo, float* __restrict__ out)
{
    __shared__ __align__(16) bf16 As[256 * 32];
    __shared__ __align__(16) bf16 Bs[256 * 32];
    __shared__ float proj_s[5 * 264];
    __shared__ float inv_s[256];

    const int tid = threadIdx.x;
    const int lane = tid & 63, w = tid >> 6;
    const int fr = lane & 15, g = lane >> 4;
    const int wj = w & 3, wi = w >> 2;            // j-quarter / i-half
    const int srow = lane >> 2, scol = (lane & 3) * 8;
    const int lofs = __builtin_amdgcn_readfirstlane(w * 1024);  // 32 rows/wave
    bf16* Asw = As + lofs;
    bf16* Bsw = Bs + lofs;
    const f32x4 vz = {0.f, 0.f, 0.f, 0.f};
    const int bid = blockIdx.x;

    if (bid >= 64) {
        const int b0 = bid - 64;
        const int wid = (b0 & 7) * 128 + (b0 >> 3);   // T1: 2 z per XCD
        const int z = wid >> 6;
        const int t = wid & 63;
        const int row0 = (t >> 3) * 256;   // i
        const int col0 = (t & 7) * 256;    // j
        const int b = z >> 3, h = z & 7;

        if (tid < 256) {
            const float* pr = proj + (size_t)(b * Tsz + row0 + tid) * 8;
#pragma unroll
            for (int c = 0; c < 5; ++c) proj_s[c * 264 + tid] = pr[c] * SCL2;
        } else {
            inv_s[tid - 256] = log2f(invs_g[(size_t)z * Tsz + row0 + (tid - 256)]);
        }

        const bf16* Ag = tk + (size_t)(b * Tsz + col0 + w * 32 + srow) * Dsz + h * DH + scol;
        const bf16* Bg = tq + (size_t)(b * Tsz + row0 + w * 32 + srow) * Dsz + h * DH + scol;

        f32x4 acc[4][8];   // [jf][ii]
#pragma unroll
        for (int m = 0; m < 4; ++m)
#pragma unroll
            for (int n = 0; n < 8; ++n) acc[m][n] = vz;

#pragma unroll 1
        for (int k0 = 0; k0 < DH; k0 += 32) {
            __syncthreads();
            gload16(Ag + k0, Asw);
            gload16(Ag + 16 * Dsz + k0, Asw + 16 * 32);
            gload16(Bg + k0, Bsw);
            gload16(Bg + 16 * Dsz + k0, Bsw + 16 * 32);
            __syncthreads();
            short8 af[4], bfv[8];
#pragma unroll
            for (int jf = 0; jf < 4; ++jf)
                af[jf] = *(const short8*)(As + (wj * 64 + jf * 16 + fr) * 32 + g * 8);
#pragma unroll
            for (int ii = 0; ii < 8; ++ii)
                bfv[ii] = *(const short8*)(Bs + (wi * 128 + ii * 16 + fr) * 32 + g * 8);
#pragma unroll
            for (int jf = 0; jf < 4; ++jf)
#pragma unroll
                for (int ii = 0; ii < 8; ++ii)
                    acc[jf][ii] = __builtin_amdgcn_mfma_f32_16x16x32_bf16(
                        af[jf], bfv[ii], acc[jf][ii], 0, 0, 0);
        }

        float* C = Wt + (size_t)z * Tsz * Tsz;
        const int dmin = col0 - (row0 + 255);
        const int dmax = (col0 + 255) - row0;
        if (dmin >= 2 || dmax <= -2) {
            const int c = (dmin >= 2) ? 4 : 0;
#pragma unroll
            for (int ii = 0; ii < 8; ++ii) {
                const int il = wi * 128 + ii * 16 + fr;
                const int gi = row0 + il;
                const float cb = proj_s[c * 264 + il] + inv_s[il];
#pragma unroll
                for (int jf = 0; jf < 4; ++jf) {
                    const int jb = col0 + wj * 64 + jf * 16 + g * 4;
                    f32x4 o;
#pragma unroll
                    for (int r = 0; r < 4; ++r)
                        o[r] = fexp2(fmaf(acc[jf][ii][r], SCL2, cb));
                    __builtin_nontemporal_store(o, (f32x4*)(C + (size_t)gi * Tsz + jb));
                }
            }
        } else {
#pragma unroll
            for (int ii = 0; ii < 8; ++ii) {
                const int il = wi * 128 + ii * 16 + fr;
                const int gi = row0 + il;
                const float liv = inv_s[il];
#pragma unroll
                for (int jf = 0; jf < 4; ++jf) {
                    const int jb = col0 + wj * 64 + jf * 16 + g * 4;
                    f32x4 o;
#pragma unroll
                    for (int r = 0; r < 4; ++r) {
                        int rel = (jb + r) - gi;
                        rel = rel < -2 ? -2 : (rel > 2 ? 2 : rel);
                        const float cb = proj_s[(rel + 2) * 264 + il] + liv;
                        o[r] = fexp2(fmaf(acc[jf][ii][r], SCL2, cb));
                    }
                    __builtin_nontemporal_store(o, (f32x4*)(C + (size_t)gi * Tsz + jb));
                }
            }
        }
    } else {
        const int row0 = (bid >> 2) * 256;   // i (16 tiles)
        const int col0 = (bid & 3) * 256;    // out col (4 tiles)
        const bf16* Ag = ctx + (size_t)(row0 + w * 32 + srow) * Dsz + scol;
        const bf16* Bg = Wob + (size_t)(col0 + w * 32 + srow) * Dsz + scol;

        f32x4 acc2[8][4];  // [ii][jc]
#pragma unroll
        for (int m = 0; m < 8; ++m)
#pragma unroll
            for (int n = 0; n < 4; ++n) acc2[m][n] = vz;

#pragma unroll 1
        for (int k0 = 0; k0 < Dsz; k0 += 32) {
            __syncthreads();
            gload16(Ag + k0, Asw);
            gload16(Ag + 16 * Dsz + k0, Asw + 16 * 32);
            gload16(Bg + k0, Bsw);
            gload16(Bg + 16 * Dsz + k0, Bsw + 16 * 32);
            __syncthreads();
            short8 af[8], bfv[4];
#pragma unroll
            for (int ii = 0; ii < 8; ++ii)
                af[ii] = *(const short8*)(As + (wi * 128 + ii * 16 + fr) * 32 + g * 8);
#pragma unroll
            for (int jc = 0; jc < 4; ++jc)
                bfv[jc] = *(const short8*)(Bs + (wj * 64 + jc * 16 + fr) * 32 + g * 8);
#pragma unroll
            for (int ii = 0; ii < 8; ++ii)
#pragma unroll
                for (int jc = 0; jc < 4; ++jc)
                    acc2[ii][jc] = __builtin_amdgcn_mfma_f32_16x16x32_bf16(
                        af[ii], bfv[jc], acc2[ii][jc], 0, 0, 0);
        }

#pragma unroll
        for (int ii = 0; ii < 8; ++ii) {
#pragma unroll
            for (int r = 0; r < 4; ++r) {
                const int gi = row0 + wi * 128 + ii * 16 + g * 4 + r;
#pragma unroll
                for (int jc = 0; jc < 4; ++jc) {
                    const int gj = col0 + wj * 64 + jc * 16 + fr;
                    out[(size_t)gi * Dsz + gj] = acc2[ii][jc][r] + bo[gj];
                }
            }
        }
    }
}

// ---------------------------------------------------------------------------
extern "C" void kernel_launch(void* const* d_in, const int* in_sizes, int n_in,
                              void* d_out, int out_size, void* d_ws, size_t ws_size,
                              hipStream_t stream)
{
    const float* query  = (const float*)d_in[0];
    const float* keys   = (const float*)d_in[1];
    const float* values = (const float*)d_in[2];
    const float* Wq = (const float*)d_in[3];
    const float* bq = (const float*)d_in[4];
    const float* Wk = (const float*)d_in[5];
    const float* bk = (const float*)d_in[6];
    const float* Wv = (const float*)d_in[7];
    const float* bv = (const float*)d_in[8];
    const float* Wo = (const float*)d_in[9];
    const float* bo = (const float*)d_in[10];
    const float* table = (const float*)d_in[11];

    float* out     = (float*)d_out;                      // B*T*D fp32
    float* weights = out + (size_t)Bsz * Tsz * Dsz;      // B*H*T*T fp32

    char* wp = (char*)d_ws;
    bf16* tq  = (bf16*)(wp);
    bf16* tk  = (bf16*)(wp + 8  * 1024 * 1024);
    bf16* vt  = (bf16*)(wp + 16 * 1024 * 1024);          // V in [z][d][j] layout
    bf16* ctx = (bf16*)(wp + 24 * 1024 * 1024);
    bf16* Wqb = (bf16*)(wp + 32 * 1024 * 1024);
    bf16* Wkb = (bf16*)(wp + 34 * 1024 * 1024);
    bf16* Wvb = (bf16*)(wp + 36 * 1024 * 1024);
    bf16* Wob = (bf16*)(wp + 38 * 1024 * 1024);
    float* proj   = (float*)(wp + 40 * 1024 * 1024);
    float* invs_g = (float*)(wp + 41 * 1024 * 1024);

    const dim3 blk(256);

    CvtArgs ca;
    ca.j[0] = { Wq, Wqb, Dsz * Dsz };
    ca.j[1] = { Wk, Wkb, Dsz * Dsz };
    ca.j[2] = { Wv, Wvb, Dsz * Dsz };
    ca.j[3] = { Wo, Wob, Dsz * Dsz };
    cvt_k<<<dim3(128, 4), blk, 0, stream>>>(ca);

    GemmArgs ga;
    ga.j[0] = { query,  Wqb, bq, tq, 1 };
    ga.j[1] = { keys,   Wkb, bk, tk, 1 };
    ga.j[2] = { values, Wvb, bv, vt, 2 };
    gemm_qkv_k<<<dim3(768), blk, 0, stream>>>(ga);

    relproj_k<<<dim3(Bsz * Tsz / 4), blk, 0, stream>>>(tq, table, proj);

    flash_pv_k<<<dim3(256), dim3(512), 0, stream>>>(
        tq, tk, vt, proj, invs_g, ctx);

    wo_k<<<dim3(64 + 1024), dim3(512), 0, stream>>>(
        tq, tk, proj, invs_g, weights, ctx, Wob, bo, out);
}